// Round 15
// baseline (390.857 us; speedup 1.0000x reference)
//
#include <hip/hip_runtime.h>

#define SEQ 2048
#define DM 256
#define NH 8
#define DKH 32
#define NBATCH 4
#define QSCALE (0.17677669529663687f * 1.4426950408889634f)   // fold log2(e): p = exp2(s)

#if __has_builtin(__builtin_amdgcn_exp2f)
#define EXP2(x) __builtin_amdgcn_exp2f(x)
#else
#define EXP2(x) exp2f(x)
#endif

typedef __attribute__((ext_vector_type(8))) __bf16 bf16x8;
typedef __attribute__((ext_vector_type(4))) float floatx4;
typedef __attribute__((ext_vector_type(8))) short short8v;
typedef __attribute__((ext_vector_type(2))) unsigned int uint2v;

__device__ inline unsigned short f2bf(float x){
  union { float f; unsigned u; } v; v.f = x;
  unsigned r = v.u + 0x7FFFu + ((v.u >> 16) & 1u);
  return (unsigned short)(r >> 16);
}
// trunc-pack two floats' high halves into one dword (low=a): 1x v_perm_b32
__device__ inline unsigned pack2bf(float a, float b){
  union { float f; unsigned u; } ua, ub; ua.f = a; ub.f = b;
  return __builtin_amdgcn_perm(ub.u, ua.u, 0x07060302u);
}

// ------------------------------------------- LayerNorm fp32 in -> bf16 out
__global__ __launch_bounds__(256) void ln_kernel(const float* __restrict__ X,
    const float* __restrict__ G, const float* __restrict__ Bv,
    unsigned short* __restrict__ Y){
  int row = blockIdx.x*4 + (threadIdx.x>>6);
  int lane = threadIdx.x & 63;
  const float4 v = *(const float4*)(X + (size_t)row*DM + lane*4);
  float s = v.x+v.y+v.z+v.w;
  #pragma unroll
  for (int off=32; off; off>>=1) s += __shfl_xor(s, off, 64);
  float mean = s * (1.0f/DM);
  float dx=v.x-mean, dy=v.y-mean, dz=v.z-mean, dw=v.w-mean;
  float ss = dx*dx+dy*dy+dz*dz+dw*dw;
  #pragma unroll
  for (int off=32; off; off>>=1) ss += __shfl_xor(ss, off, 64);
  float r = rsqrtf(ss*(1.0f/DM) + 1e-6f);
  const float4 g = *(const float4*)(G + lane*4);
  const float4 b = *(const float4*)(Bv + lane*4);
  ushort4 o;
  o.x = f2bf(dx*r*g.x + b.x);
  o.y = f2bf(dy*r*g.y + b.y);
  o.z = f2bf(dz*r*g.z + b.z);
  o.w = f2bf(dw*r*g.w + b.w);
  *(ushort4*)(Y + (size_t)row*DM + lane*4) = o;
}

// ------ batched prep: 11 weight transposes + x -> bf16 into A_cat cols 1024..
struct WtArgs {
  const float* src[12];
  unsigned short* dst[12];
  int K[12], N[12], stride[12], off[12];
  int blk0[13];
};
__global__ __launch_bounds__(256) void wtrans_all(WtArgs a){
  __shared__ unsigned short sT[64][40];
  int wi = 0;
  while (blockIdx.x >= (unsigned)a.blk0[wi+1]) ++wi;
  int blk = blockIdx.x - a.blk0[wi];
  int tid = threadIdx.x;
  if (wi == 11){
    const float* X = a.src[11];
    unsigned short* D = a.dst[11];
    int row = blk*8 + (tid>>5);
    int c8 = (tid & 31)*8;
    const float* ip = X + (size_t)row*256 + c8;
    float4 v0 = *(const float4*)ip, v1 = *(const float4*)(ip+4);
    union { short8v v; unsigned short u[8]; } pk;
    pk.u[0]=f2bf(v0.x); pk.u[1]=f2bf(v0.y); pk.u[2]=f2bf(v0.z); pk.u[3]=f2bf(v0.w);
    pk.u[4]=f2bf(v1.x); pk.u[5]=f2bf(v1.y); pk.u[6]=f2bf(v1.z); pk.u[7]=f2bf(v1.w);
    *(short8v*)(D + (size_t)row*1280 + 1024 + c8) = pk.v;
    return;
  }
  const float* W = a.src[wi];
  unsigned short* Wt = a.dst[wi];
  int K = a.K[wi], N = a.N[wi], stride = a.stride[wi], off = a.off[wi];
  int nbk = N >> 6;
  int bx = blk % nbk, by = blk / nbk;
  int k0 = by << 5, n0 = bx << 6;
  int r = tid >> 3, cs = (tid & 7) << 3;
  const float* ip = W + (size_t)(k0+r)*N + n0 + cs;
  float4 av = *(const float4*)ip;
  float4 bq = *(const float4*)(ip+4);
  sT[cs+0][r]=f2bf(av.x); sT[cs+1][r]=f2bf(av.y); sT[cs+2][r]=f2bf(av.z); sT[cs+3][r]=f2bf(av.w);
  sT[cs+4][r]=f2bf(bq.x); sT[cs+5][r]=f2bf(bq.y); sT[cs+6][r]=f2bf(bq.z); sT[cs+7][r]=f2bf(bq.w);
  __syncthreads();
  int n = tid >> 2, kc = (tid & 3) << 3;
  *(short8v*)(Wt + (size_t)(n0+n)*stride + off + k0 + kc) = *(const short8v*)(&sT[n][kc]);
}

// ---------------------------------------------- bf16 MFMA GEMM, 128x64 tile
__global__ __launch_bounds__(256) void gemm_bf16(const unsigned short* __restrict__ A,
    const unsigned short* __restrict__ Bt, const float* __restrict__ bias,
    const float* __restrict__ Res, void* __restrict__ Cout,
    int M, int N, int K, int flags, float outscale, int ldc){
  __shared__ unsigned short sA[8192];
  __shared__ unsigned short sB[4096];
  int nbk = N >> 6;
  int bx = blockIdx.x % nbk, by = blockIdx.x / nbk;
  int m0 = by << 7, n0 = bx << 6;
  int tid = threadIdx.x, w = tid >> 6, lane = tid & 63;
  int m16 = lane & 15, quad = lane >> 4;
  int wr = w & 1, wc = w >> 1;
  const unsigned short* pa[4]; const unsigned short* pb[2];
  #pragma unroll
  for (int i=0;i<4;++i){
    int c = tid + i*256;
    int l = c & 63, kk = (c>>6)&1, mt = c>>7;
    pa[i] = A + (size_t)(m0 + mt*16 + (l&15))*K + kk*32 + ((l>>4)<<3);
  }
  #pragma unroll
  for (int i=0;i<2;++i){
    int c = tid + i*256;
    int l = c & 63, kk = (c>>6)&1, nt = c>>7;
    pb[i] = Bt + (size_t)(n0 + nt*16 + (l&15))*K + kk*32 + ((l>>4)<<3);
  }
  short8v ar[4], br[2];
  #pragma unroll
  for (int i=0;i<4;++i) ar[i] = *(const short8v*)pa[i];
  #pragma unroll
  for (int i=0;i<2;++i) br[i] = *(const short8v*)pb[i];
  floatx4 acc[4][2];
  #pragma unroll
  for (int i=0;i<4;++i){ acc[i][0]=(floatx4){0,0,0,0}; acc[i][1]=(floatx4){0,0,0,0}; }
  for (int k0=0; k0<K; k0+=64){
    __syncthreads();
    #pragma unroll
    for (int i=0;i<4;++i) *(short8v*)(sA + (tid+i*256)*8) = ar[i];
    #pragma unroll
    for (int i=0;i<2;++i) *(short8v*)(sB + (tid+i*256)*8) = br[i];
    __syncthreads();
    if (k0 + 64 < K){
      #pragma unroll
      for (int i=0;i<4;++i) ar[i] = *(const short8v*)(pa[i] + k0 + 64);
      #pragma unroll
      for (int i=0;i<2;++i) br[i] = *(const short8v*)(pb[i] + k0 + 64);
    }
    #pragma unroll
    for (int kk=0;kk<2;++kk){
      bf16x8 bf0 = *(const bf16x8*)(sB + (((wc*2+0)*2+kk)*64 + lane)*8);
      bf16x8 bf1 = *(const bf16x8*)(sB + (((wc*2+1)*2+kk)*64 + lane)*8);
      #pragma unroll
      for (int mt=0;mt<4;++mt){
        bf16x8 af = *(const bf16x8*)(sA + (((wr*4+mt)*2+kk)*64 + lane)*8);
        acc[mt][0] = __builtin_amdgcn_mfma_f32_16x16x32_bf16(af, bf0, acc[mt][0], 0,0,0);
        acc[mt][1] = __builtin_amdgcn_mfma_f32_16x16x32_bf16(af, bf1, acc[mt][1], 0,0,0);
      }
    }
  }
  float b0 = bias ? bias[n0 + wc*32 + m16]      : 0.0f;
  float b1 = bias ? bias[n0 + wc*32 + 16 + m16] : 0.0f;
  #pragma unroll
  for (int mt=0;mt<4;++mt){
    #pragma unroll
    for (int r=0;r<4;++r){
      size_t row = (size_t)m0 + wr*64 + mt*16 + quad*4 + r;
      int col0 = n0 + wc*32 + m16, col1 = col0 + 16;
      float v0 = acc[mt][0][r] + b0, v1 = acc[mt][1][r] + b1;
      if (Res){ v0 += Res[row*N + col0]; v1 += Res[row*N + col1]; }
      if (flags & 1){ v0 = fmaxf(v0, 0.0f); v1 = fmaxf(v1, 0.0f); }
      v0 *= outscale; v1 *= outscale;
      if (flags & 2){
        unsigned short* C = (unsigned short*)Cout;
        C[row*ldc + col0] = f2bf(v0); C[row*ldc + col1] = f2bf(v1);
      } else {
        float* C = (float*)Cout;
        C[row*ldc + col0] = v0; C[row*ldc + col1] = v1;
      }
    }
  }
}

// --------------------------------------------- bf16 MFMA GEMM, 64x64 tile
__global__ __launch_bounds__(256) void gemm64(const unsigned short* __restrict__ A,
    const unsigned short* __restrict__ Bt, const float* __restrict__ bias,
    const float* __restrict__ bias2, const float* __restrict__ Res,
    void* __restrict__ Cout, int M, int N, int K, int flags, float outscale){
  __shared__ unsigned short sA[4096];
  __shared__ unsigned short sB[4096];
  int nbk = N >> 6;
  int bx = blockIdx.x % nbk, by = blockIdx.x / nbk;
  int m0 = by << 6, n0 = bx << 6;
  int tid = threadIdx.x, w = tid >> 6, lane = tid & 63;
  int m16 = lane & 15, quad = lane >> 4;
  int wr = w & 1, wc = w >> 1;
  const unsigned short* pa[2]; const unsigned short* pb[2];
  #pragma unroll
  for (int i=0;i<2;++i){
    int c = tid + i*256;
    int l = c & 63, kk = (c>>6)&1, mt = c>>7;
    int col = kk*32 + ((l>>4)<<3);
    pa[i] = A  + (size_t)(m0 + mt*16 + (l&15))*K + col;
    pb[i] = Bt + (size_t)(n0 + mt*16 + (l&15))*K + col;
  }
  short8v ar[2], br[2];
  #pragma unroll
  for (int i=0;i<2;++i){ ar[i] = *(const short8v*)pa[i]; br[i] = *(const short8v*)pb[i]; }
  floatx4 acc[2][2];
  acc[0][0]=(floatx4){0,0,0,0}; acc[0][1]=(floatx4){0,0,0,0};
  acc[1][0]=(floatx4){0,0,0,0}; acc[1][1]=(floatx4){0,0,0,0};
  for (int k0=0; k0<K; k0+=64){
    __syncthreads();
    #pragma unroll
    for (int i=0;i<2;++i){
      *(short8v*)(sA + (tid+i*256)*8) = ar[i];
      *(short8v*)(sB + (tid+i*256)*8) = br[i];
    }
    __syncthreads();
    if (k0 + 64 < K){
      #pragma unroll
      for (int i=0;i<2;++i){ ar[i] = *(const short8v*)(pa[i]+k0+64); br[i] = *(const short8v*)(pb[i]+k0+64); }
    }
    #pragma unroll
    for (int kk=0;kk<2;++kk){
      bf16x8 bf0 = *(const bf16x8*)(sB + (((wc*2+0)*2+kk)*64 + lane)*8);
      bf16x8 bf1 = *(const bf16x8*)(sB + (((wc*2+1)*2+kk)*64 + lane)*8);
      bf16x8 af0 = *(const bf16x8*)(sA + (((wr*2+0)*2+kk)*64 + lane)*8);
      bf16x8 af1 = *(const bf16x8*)(sA + (((wr*2+1)*2+kk)*64 + lane)*8);
      acc[0][0] = __builtin_amdgcn_mfma_f32_16x16x32_bf16(af0, bf0, acc[0][0], 0,0,0);
      acc[0][1] = __builtin_amdgcn_mfma_f32_16x16x32_bf16(af0, bf1, acc[0][1], 0,0,0);
      acc[1][0] = __builtin_amdgcn_mfma_f32_16x16x32_bf16(af1, bf0, acc[1][0], 0,0,0);
      acc[1][1] = __builtin_amdgcn_mfma_f32_16x16x32_bf16(af1, bf1, acc[1][1], 0,0,0);
    }
  }
  float b0 = bias ? bias[n0 + wc*32 + m16]      : 0.0f;
  float b1 = bias ? bias[n0 + wc*32 + 16 + m16] : 0.0f;
  if (bias2){ b0 += bias2[n0 + wc*32 + m16]; b1 += bias2[n0 + wc*32 + 16 + m16]; }
  #pragma unroll
  for (int mt=0;mt<2;++mt){
    #pragma unroll
    for (int r=0;r<4;++r){
      size_t row = (size_t)m0 + (wr*2+mt)*16 + quad*4 + r;
      int col0 = n0 + wc*32 + m16, col1 = col0 + 16;
      float v0 = acc[mt][0][r] + b0, v1 = acc[mt][1][r] + b1;
      if (Res){ v0 += Res[row*N + col0]; v1 += Res[row*N + col1]; }
      if (flags & 1){ v0 = fmaxf(v0, 0.0f); v1 = fmaxf(v1, 0.0f); }
      v0 *= outscale; v1 *= outscale;
      if (flags & 2){
        unsigned short* C = (unsigned short*)Cout;
        C[row*N + col0] = f2bf(v0); C[row*N + col1] = f2bf(v1);
      } else {
        float* C = (float*)Cout;
        C[row*N + col0] = v0; C[row*N + col1] = v1;
      }
    }
  }
}

// ---------------------- fused QKV GEMM: A[8192x256] @ wqkv[768x256]^T
// seg2 -> V transposed into Vt[(b*8+h)*32+d][t'] with SLOT-PERMUTED t':
// within each 32-key group, slot = quad*8 + half*4 + (t&3) so flash's PV
// A-fragment is the lane's own packed P registers (no LDS P round-trip).
__global__ __launch_bounds__(256) void gemm_qkv(const unsigned short* __restrict__ A,
    const unsigned short* __restrict__ Bt,
    const float* __restrict__ bq, const float* __restrict__ bk, const float* __restrict__ bv,
    unsigned short* __restrict__ outq, unsigned short* __restrict__ outk,
    unsigned short* __restrict__ outvt){
  __shared__ unsigned short sA[8192];
  __shared__ unsigned short sB[4096];
  int bx = blockIdx.x % 12, by = blockIdx.x / 12;
  int m0 = by << 7, n0 = bx << 6;
  int tid = threadIdx.x, w = tid >> 6, lane = tid & 63;
  int m16 = lane & 15, quad = lane >> 4;
  int wr = w & 1, wc = w >> 1;
  const unsigned short* pa[4]; const unsigned short* pb[2];
  #pragma unroll
  for (int i=0;i<4;++i){
    int c = tid + i*256;
    int l = c & 63, kk = (c>>6)&1, mt = c>>7;
    pa[i] = A + (size_t)(m0 + mt*16 + (l&15))*256 + kk*32 + ((l>>4)<<3);
  }
  #pragma unroll
  for (int i=0;i<2;++i){
    int c = tid + i*256;
    int l = c & 63, kk = (c>>6)&1, nt = c>>7;
    pb[i] = Bt + (size_t)(n0 + nt*16 + (l&15))*256 + kk*32 + ((l>>4)<<3);
  }
  short8v ar[4], br[2];
  #pragma unroll
  for (int i=0;i<4;++i) ar[i] = *(const short8v*)pa[i];
  #pragma unroll
  for (int i=0;i<2;++i) br[i] = *(const short8v*)pb[i];
  floatx4 acc[4][2];
  #pragma unroll
  for (int i=0;i<4;++i){ acc[i][0]=(floatx4){0,0,0,0}; acc[i][1]=(floatx4){0,0,0,0}; }
  for (int k0=0; k0<256; k0+=64){
    __syncthreads();
    #pragma unroll
    for (int i=0;i<4;++i) *(short8v*)(sA + (tid+i*256)*8) = ar[i];
    #pragma unroll
    for (int i=0;i<2;++i) *(short8v*)(sB + (tid+i*256)*8) = br[i];
    __syncthreads();
    if (k0 + 64 < 256){
      #pragma unroll
      for (int i=0;i<4;++i) ar[i] = *(const short8v*)(pa[i] + k0 + 64);
      #pragma unroll
      for (int i=0;i<2;++i) br[i] = *(const short8v*)(pb[i] + k0 + 64);
    }
    #pragma unroll
    for (int kk=0;kk<2;++kk){
      bf16x8 bf0 = *(const bf16x8*)(sB + (((wc*2+0)*2+kk)*64 + lane)*8);
      bf16x8 bf1 = *(const bf16x8*)(sB + (((wc*2+1)*2+kk)*64 + lane)*8);
      #pragma unroll
      for (int mt=0;mt<4;++mt){
        bf16x8 af = *(const bf16x8*)(sA + (((wr*4+mt)*2+kk)*64 + lane)*8);
        acc[mt][0] = __builtin_amdgcn_mfma_f32_16x16x32_bf16(af, bf0, acc[mt][0], 0,0,0);
        acc[mt][1] = __builtin_amdgcn_mfma_f32_16x16x32_bf16(af, bf1, acc[mt][1], 0,0,0);
      }
    }
  }
  int seg = n0 >> 8;
  int nb  = n0 & 255;
  const float* bias = (seg==0) ? bq : ((seg==1) ? bk : bv);
  float b0 = bias[nb + wc*32 + m16];
  float b1 = bias[nb + wc*32 + 16 + m16];
  if (seg == 2){
    int b = m0 >> 11;
    int t0 = (m0 & 2047) + wr*64 + quad*4;
    #pragma unroll
    for (int mt=0;mt<4;++mt){
      int tt = t0 + mt*16;
      // slot permutation within 32-key group (tt is 4-aligned)
      int tp = (tt & ~31) | (((tt>>2)&3)<<3) | (((tt>>4)&1)<<2);
      #pragma unroll
      for (int cc=0;cc<2;++cc){
        int col = nb + wc*32 + m16 + cc*16;
        float bb = cc ? b1 : b0;
        int hh = col >> 5, dd = col & 31;
        uint2v pk;
        pk.x = (unsigned)f2bf(acc[mt][cc][0]+bb) | ((unsigned)f2bf(acc[mt][cc][1]+bb) << 16);
        pk.y = (unsigned)f2bf(acc[mt][cc][2]+bb) | ((unsigned)f2bf(acc[mt][cc][3]+bb) << 16);
        *(uint2v*)(outvt + ((size_t)((b*8+hh)*32+dd))*SEQ + tp) = pk;
      }
    }
  } else {
    unsigned short* C = (seg==0) ? outq : outk;
    float scale = (seg==0) ? QSCALE : 1.0f;
    #pragma unroll
    for (int mt=0;mt<4;++mt){
      #pragma unroll
      for (int r=0;r<4;++r){
        size_t row = (size_t)m0 + wr*64 + mt*16 + quad*4 + r;
        int col0 = nb + wc*32 + m16, col1 = col0 + 16;
        C[row*256 + col0] = f2bf((acc[mt][0][r] + b0)*scale);
        C[row*256 + col1] = f2bf((acc[mt][1][r] + b1)*scale);
      }
    }
  }
}

// ---------------- flash v8: S^T, P-in-registers (slot-permuted V), 2-way key
// split. grid = 2048: [half][bh][qb]; 4 waves x 16 q; LDS 16.4KB -> 8 blk/CU.
__global__ __launch_bounds__(256, 8) void flash_kernel(
    const unsigned short* __restrict__ Qb, const unsigned short* __restrict__ Kb,
    const unsigned short* __restrict__ Vt, float* __restrict__ opart,
    float* __restrict__ lpart){
  __shared__ unsigned short sK[4096];         // (kt*64+lane)*8, key=kt*16+(l&15)
  __shared__ unsigned short sV[4096];         // ((ks*2+nt)*64+lane)*8, slot order
  int qb = blockIdx.x & 31;
  int bh = (blockIdx.x >> 5) & 31;
  int half = blockIdx.x >> 10;
  int h = bh & 7, b = bh >> 3;
  int tid = threadIdx.x, w = tid >> 6, lane = tid & 63;
  int m16 = lane & 15, quad = lane >> 4;
  int qrow0 = qb*64 + w*16;
  bf16x8 qf = *(const bf16x8*)(Qb + (size_t)(b*SEQ + qrow0 + m16)*DM + h*DKH + quad*8);
  floatx4 o0 = {0,0,0,0}, o1 = {0,0,0,0};
  float l0 = 0.f;
  int tbeg = half*1024;

  const unsigned short* kp[2]; const unsigned short* vp[2];
  #pragma unroll
  for (int i=0;i<2;++i){
    int c = tid + i*256, l = c & 63;
    int kt = c >> 6;
    kp[i] = Kb + (size_t)(b*SEQ + kt*16 + (l&15))*DM + h*DKH + ((l>>4)<<3);
    int nt = (c>>6)&1, ks = c>>7;
    vp[i] = Vt + (size_t)(bh*DKH + nt*16 + (l&15))*SEQ + ks*32 + ((l>>4)<<3);
  }
  short8v kr[2], vr[2];
  #pragma unroll
  for (int i=0;i<2;++i){
    kr[i] = *(const short8v*)(kp[i] + (size_t)tbeg*DM);
    vr[i] = *(const short8v*)(vp[i] + tbeg);
  }

  for (int t0=tbeg; t0<tbeg+1024; t0+=128){
    __syncthreads();
    #pragma unroll
    for (int i=0;i<2;++i){
      *(short8v*)(sK + (tid+i*256)*8) = kr[i];
      *(short8v*)(sV + (tid+i*256)*8) = vr[i];
    }
    __syncthreads();
    if (t0 + 128 < tbeg + 1024){
      #pragma unroll
      for (int i=0;i<2;++i){
        kr[i] = *(const short8v*)(kp[i] + (size_t)(t0+128)*DM);
        vr[i] = *(const short8v*)(vp[i] + (t0+128));
      }
    }
    // per 32-key group: two S^T MFMAs -> exp -> pack -> PV A-frag IN REGISTERS
    #pragma unroll
    for (int ks=0;ks<4;++ks){
      bf16x8 kf0 = *(const bf16x8*)(sK + ((ks*2+0)*64+lane)*8);
      bf16x8 kf1 = *(const bf16x8*)(sK + ((ks*2+1)*64+lane)*8);
      floatx4 z = {0,0,0,0};
      floatx4 s0 = __builtin_amdgcn_mfma_f32_16x16x32_bf16(kf0, qf, z, 0,0,0);
      floatx4 s1 = __builtin_amdgcn_mfma_f32_16x16x32_bf16(kf1, qf, z, 0,0,0);
      float p0 = EXP2(s0[0]), p1 = EXP2(s0[1]), p2 = EXP2(s0[2]), p3 = EXP2(s0[3]);
      float p4 = EXP2(s1[0]), p5 = EXP2(s1[1]), p6 = EXP2(s1[2]), p7 = EXP2(s1[3]);
      l0 += ((p0+p1)+(p2+p3)) + ((p4+p5)+(p6+p7));
      union { bf16x8 v; unsigned u[4]; } pf;
      pf.u[0] = pack2bf(p0,p1); pf.u[1] = pack2bf(p2,p3);
      pf.u[2] = pack2bf(p4,p5); pf.u[3] = pack2bf(p6,p7);
      bf16x8 vf0 = *(const bf16x8*)(sV + ((ks*2+0)*64+lane)*8);
      bf16x8 vf1 = *(const bf16x8*)(sV + ((ks*2+1)*64+lane)*8);
      o0 = __builtin_amdgcn_mfma_f32_16x16x32_bf16(pf.v, vf0, o0, 0,0,0);
      o1 = __builtin_amdgcn_mfma_f32_16x16x32_bf16(pf.v, vf1, o1, 0,0,0);
    }
  }
  // l0: per-lane partial for q = qrow0+m16 over this lane's keys; sum quads
  l0 += __shfl_xor(l0, 16, 64);
  l0 += __shfl_xor(l0, 32, 64);
  if (quad == 0)
    lpart[(size_t)half*65536 + bh*2048 + qrow0 + m16] = l0;
  #pragma unroll
  for (int r=0;r<4;++r){
    int q = qrow0 + quad*4 + r;
    size_t ob = ((size_t)(half*32 + bh)*2048 + q)*32;
    opart[ob + m16]      = o0[r];
    opart[ob + 16 + m16] = o1[r];
  }
}

// ---------- reduce O/l halves -> bf16 O + inv-l (for colsum)
__global__ __launch_bounds__(256) void reduce_o(const float* __restrict__ opart,
    const float* __restrict__ lpart, unsigned short* __restrict__ Obf,
    float* __restrict__ Linv){
  int e4 = blockIdx.x*256 + threadIdx.x;       // float4 index, 524288 total
  int e = e4*4;
  int row = e >> 5;                            // bh*2048 + q
  int dk0 = e & 31;
  float la = lpart[row], lb = lpart[65536 + row];
  float inv = 1.0f / (la + lb);
  float4 oa = *(const float4*)(opart + e);
  float4 ob = *(const float4*)(opart + 2097152 + e);
  int bh = row >> 11, q = row & 2047;
  int b = bh >> 3, h = bh & 7;
  ushort4 o;
  o.x = f2bf((oa.x+ob.x)*inv); o.y = f2bf((oa.y+ob.y)*inv);
  o.z = f2bf((oa.z+ob.z)*inv); o.w = f2bf((oa.w+ob.w)*inv);
  *(ushort4*)(Obf + ((size_t)(b*SEQ+q))*DM + h*DKH + dk0) = o;
  if (dk0 == 0) Linv[row] = inv;
}

// --------------- colsum: LDS-staged, q-range split x2, raw exp
__global__ __launch_bounds__(128) void colsum_kernel(
    const unsigned short* __restrict__ Qb, const unsigned short* __restrict__ Kb,
    const float* __restrict__ Lv, float* __restrict__ col){
  __shared__ unsigned short sQ[2048];
  __shared__ float sL[64];
  int kc = blockIdx.x & 31;
  int rest = blockIdx.x >> 5;
  int bh = rest & 31;
  int half = rest >> 5;
  int h = bh & 7, b = bh >> 3;
  int tid = threadIdx.x, w = tid >> 6, lane = tid & 63;
  int m16 = lane & 15, quad = lane >> 4;
  int key0 = kc*64 + w*32;
  const unsigned short* kp = Kb + (size_t)(b*SEQ + key0 + m16)*DM + h*DKH + quad*8;
  bf16x8 kf0 = *(const bf16x8*)kp;
  bf16x8 kf1 = *(const bf16x8*)(kp + 16*DM);
  float acc0[4] = {0,0,0,0}, acc1[4] = {0,0,0,0};
  const unsigned short* qp[2];
  #pragma unroll
  for (int i=0;i<2;++i){
    int c = tid + i*128, l = c & 63, qt = c >> 6;
    qp[i] = Qb + (size_t)(b*SEQ + half*1024 + qt*16 + (l&15))*DM + h*DKH + ((l>>4)<<3);
  }
  short8v qr[2];
  #pragma unroll
  for (int i=0;i<2;++i) qr[i] = *(const short8v*)qp[i];
  float lr = (tid < 64) ? Lv[(size_t)bh*SEQ + half*1024 + tid] : 0.0f;
  for (int q0=0; q0<1024; q0+=64){
    __syncthreads();
    #pragma unroll
    for (int i=0;i<2;++i) *(short8v*)(sQ + (tid+i*128)*8) = qr[i];
    if (tid < 64) sL[tid] = lr;
    __syncthreads();
    if (q0 + 64 < 1024){
      #pragma unroll
      for (int i=0;i<2;++i) qr[i] = *(const short8v*)(qp[i] + (size_t)(q0+64)*DM);
      if (tid < 64) lr = Lv[(size_t)bh*SEQ + half*1024 + q0 + 64 + tid];
    }
    floatx4 z = {0,0,0,0};
    #pragma unroll
    for (int qt2=0;qt2<4;++qt2){
      bf16x8 qf = *(const bf16x8*)(sQ + (qt2*64+lane)*8);
      floatx4 t0 = __builtin_amdgcn_mfma_f32_16x16x32_bf16(kf0, qf, z, 0,0,0);
      floatx4 t1 = __builtin_amdgcn_mfma_f32_16x16x32_bf16(kf1, qf, z, 0,0,0);
      float lq = sL[qt2*16+m16];
      #pragma unroll
      for (int r=0;r<4;++r){ acc0[r] += EXP2(t0[r])*lq; acc1[r] += EXP2(t1[r])*lq; }
    }
  }
  #pragma unroll
  for (int r=0;r<4;++r){
    float v0 = acc0[r], v1 = acc1[r];
    v0 += __shfl_xor(v0, 1, 64); v0 += __shfl_xor(v0, 2, 64);
    v0 += __shfl_xor(v0, 4, 64); v0 += __shfl_xor(v0, 8, 64);
    v1 += __shfl_xor(v1, 1, 64); v1 += __shfl_xor(v1, 2, 64);
    v1 += __shfl_xor(v1, 4, 64); v1 += __shfl_xor(v1, 8, 64);
    if (m16 == 0){
      size_t base = (size_t)(half*32 + bh)*SEQ;
      col[base + key0 + quad*4 + r]      = v0;
      col[base + key0 + 16 + quad*4 + r] = v1;
    }
  }
}

// ------------------------------------- importance = 0.7*G + 0.3*L (fp64 acc)
__global__ __launch_bounds__(128) void imp_kernel(const float* __restrict__ colG,
    const float* __restrict__ colL, float* __restrict__ imp){
  int i = blockIdx.x*128 + threadIdx.x;
  int b = i >> 11, t = i & 2047;
  double sg = 0.0, sl = 0.0;
  for (int h=0; h<8; ++h){
    size_t i0 = (size_t)(b*8+h)*SEQ + t;
    size_t i1 = (size_t)(32 + b*8+h)*SEQ + t;
    sg += (double)colG[i0] + (double)colG[i1];
    sl += (double)colL[i0] + (double)colL[i1];
  }
  imp[i] = (float)(0.7*sg + 0.3*sl);
}

// --------------------- partial ranks (desc value, asc index tie-break)
__global__ __launch_bounds__(256) void rank_part(const float* __restrict__ imp,
    int* __restrict__ rp){
  __shared__ float sj[256];
  int jc = blockIdx.x & 7;
  int ic = (blockIdx.x >> 3) & 7;
  int b  = blockIdx.x >> 6;
  int tid = threadIdx.x;
  sj[tid] = imp[b*2048 + jc*256 + tid];
  __syncthreads();
  int i = ic*256 + tid;
  float v = imp[b*2048 + i];
  int jbase = jc*256;
  int r = 0;
  #pragma unroll 4
  for (int j=0; j<256; j+=4){
    float4 vj = *(const float4*)&sj[j];
    r += (vj.x > v) || (vj.x == v && (jbase+j+0) < i);
    r += (vj.y > v) || (vj.y == v && (jbase+j+1) < i);
    r += (vj.z > v) || (vj.z == v && (jbase+j+2) < i);
    r += (vj.w > v) || (vj.w == v && (jbase+j+3) < i);
  }
  rp[(size_t)jc*8192 + b*2048 + i] = r;
}

// --------------------- compact indices with rank < KK (ascending order)
__global__ __launch_bounds__(256) void compact_kernel(const int* __restrict__ rp,
    int KK, int* __restrict__ idxout){
  __shared__ int swave[4];
  int b = blockIdx.x;
  int tid = threadIdx.x, w = tid >> 6, lane = tid & 63;
  int base = tid*8;
  int f[8]; int c = 0;
  #pragma unroll
  for (int j=0;j<8;++j){
    int rr = 0;
    #pragma unroll
    for (int c2=0;c2<8;++c2) rr += rp[(size_t)c2*8192 + b*2048 + base + j];
    f[j] = (rr < KK) ? 1 : 0; c += f[j];
  }
  int pref = c;
  #pragma unroll
  for (int off=1; off<64; off<<=1){
    int t = __shfl_up(pref, off, 64);
    if (lane >= off) pref += t;
  }
  if (lane == 63) swave[w] = pref;
  __syncthreads();
  int wbase = 0;
  for (int k=0;k<w;++k) wbase += swave[k];
  int pos = wbase + pref - c;
  #pragma unroll
  for (int j=0;j<8;++j){
    if (f[j]) idxout[b*KK + pos++] = base + j;
  }
}

// --------------------------------------- gather + BatchNorm + write idx
__global__ __launch_bounds__(256) void final_kernel(const float* __restrict__ rb,
    const int* __restrict__ idx, const float* __restrict__ g, const float* __restrict__ bt,
    const float* __restrict__ mean, const float* __restrict__ var,
    float* __restrict__ out, int KK){
  int row = blockIdx.x*4 + (threadIdx.x>>6);
  int lane = threadIdx.x & 63;
  int total = NBATCH*KK;
  if (row < total){
    int b = row / KK;
    int src = idx[row];
    float4 v  = *(const float4*)(rb + ((size_t)(b*SEQ+src))*DM + lane*4);
    float4 gm = *(const float4*)(mean + lane*4);
    float4 gv = *(const float4*)(var  + lane*4);
    float4 gg = *(const float4*)(g    + lane*4);
    float4 gb = *(const float4*)(bt   + lane*4);
    float4 o;
    o.x = (v.x-gm.x)*rsqrtf(gv.x+1e-3f)*gg.x + gb.x;
    o.y = (v.y-gm.y)*rsqrtf(gv.y+1e-3f)*gg.y + gb.y;
    o.z = (v.z-gm.z)*rsqrtf(gv.z+1e-3f)*gg.z + gb.z;
    o.w = (v.w-gm.w)*rsqrtf(gv.w+1e-3f)*gg.w + gb.w;
    *(float4*)(out + (size_t)row*DM + lane*4) = o;
  }
  int gid = blockIdx.x*256 + threadIdx.x;
  if (gid < total) out[(size_t)total*DM + gid] = (float)idx[gid];
}

// ================================================================== launch
extern "C" void kernel_launch(void* const* d_in, const int* in_sizes, int n_in,
                              void* d_out, int out_size, void* d_ws, size_t ws_size,
                              hipStream_t stream){
  (void)in_sizes; (void)n_in; (void)ws_size;
  const float* x    = (const float*)d_in[0];
  const float* ln1g = (const float*)d_in[1];
  const float* ln1b = (const float*)d_in[2];
  const float* ln2g = (const float*)d_in[3];
  const float* ln2b = (const float*)d_in[4];
  const float* ln3g = (const float*)d_in[5];
  const float* ln3b = (const float*)d_in[6];
  const float* gqw = (const float*)d_in[7];  const float* gqb = (const float*)d_in[8];
  const float* gkw = (const float*)d_in[9];  const float* gkb = (const float*)d_in[10];
  const float* gvw = (const float*)d_in[11]; const float* gvb = (const float*)d_in[12];
  const float* gow = (const float*)d_in[13]; const float* gob = (const float*)d_in[14];
  const float* lqw = (const float*)d_in[15]; const float* lqb = (const float*)d_in[16];
  const float* lkw = (const float*)d_in[17]; const float* lkb = (const float*)d_in[18];
  const float* lvw = (const float*)d_in[19]; const float* lvb = (const float*)d_in[20];
  const float* low = (const float*)d_in[21]; const float* lob = (const float*)d_in[22];
  const float* fw1 = (const float*)d_in[23]; const float* fb1 = (const float*)d_in[24];
  const float* fw2 = (const float*)d_in[25]; const float* fb2 = (const float*)d_in[26];
  const float* resw = (const float*)d_in[27]; const float* resb = (const float*)d_in[28];
  const float* bng = (const float*)d_in[29]; const float* bnb = (const float*)d_in[30];
  const float* bnm = (const float*)d_in[31]; const float* bnv = (const float*)d_in[32];

  float* ws = (float*)d_ws;
  const size_t M1 = 2097152;                 // B*S*D
  float* r1 = ws;
  float* r2 = ws + M1;
  float* r3 = ws + 2*M1;
  unsigned short* nb  = (unsigned short*)(ws + 3*M1);
  unsigned short* qbf = (unsigned short*)(ws + 3*M1 + M1/2);
  unsigned short* kbf = (unsigned short*)(ws + 4*M1);
  unsigned short* vtb = (unsigned short*)(ws + 4*M1 + M1/2);
  unsigned short* obf = (unsigned short*)(ws + 5*M1);
  unsigned short* Acat = (unsigned short*)(ws + 6*M1);  // 8192x1280 bf16: 6*M1..8.5*M1
  unsigned short* wT  = (unsigned short*)(ws + 9*M1);
  unsigned short* wgq = wT;            unsigned short* wgk = wT + 65536;
  unsigned short* wgv = wT + 131072;   unsigned short* wgo = wT + 196608;
  unsigned short* wlq = wT + 262144;   unsigned short* wlk = wT + 327680;
  unsigned short* wlv = wT + 393216;   unsigned short* wlo = wT + 458752;
  unsigned short* wf1  = wT + 524288;  // [1024][256]
  unsigned short* wcat = wT + 786432;  // [256][1280] = wf2^T | resw^T
  float* Ls    = ws + 10*M1;                      // 65536 (inv l)
  float* lpart = ws + 10*M1 + 65536;              // 2 x 65536 raw l halves
  float* colG  = ws + 10*M1 + 196608;             // 2 x 32 bh x 2048
  float* colL  = ws + 10*M1 + 327680;
  float* impb  = ws + 10*M1 + 458752;             // 8192
  int*   rpb   = (int*)(ws + 10*M1 + 466944);     // 8 x 8192 partial ranks
  int*   idxb  = (int*)(ws + 10*M1 + 532480);
  float* opart = ws + 11*M1;                      // 2*M1 floats: 11*M1..13*M1 (NO overlap w/ Acat)

  int KK = out_size / (NBATCH*(DM+1));
  float* out = (float*)d_out;

  // ---- prep: 11 weight transposes + x->bf16 into Acat cols 1024.. (one launch)
  WtArgs wa;
  const float* srcs[12] = {gqw,gkw,gvw,gow,lqw,lkw,lvw,low, fw1, fw2, resw, x};
  unsigned short* dsts[12] = {wgq,wgk,wgv,wgo,wlq,wlk,wlv,wlo, wf1, wcat, wcat, Acat};
  int Ks[12]  = {256,256,256,256,256,256,256,256, 256, 1024, 256, 0};
  int Ns[12]  = {256,256,256,256,256,256,256,256, 1024, 256, 256, 0};
  int Ss[12]  = {256,256,256,256,256,256,256,256, 256, 1280, 1280, 0};
  int Os[12]  = {0,0,0,0,0,0,0,0, 0, 0, 1024, 0};
  int acc = 0;
  for (int i=0;i<12;++i){
    wa.src[i]=srcs[i]; wa.dst[i]=dsts[i]; wa.K[i]=Ks[i]; wa.N[i]=Ns[i];
    wa.stride[i]=Ss[i]; wa.off[i]=Os[i];
    wa.blk0[i]=acc;
    acc += (i==11) ? 1024 : (Ks[i]>>5)*(Ns[i]>>6);
  }
  wa.blk0[12]=acc;
  wtrans_all<<<acc,256,0,stream>>>(wa);

  // ---- block 1: global attention
  ln_kernel<<<2048,256,0,stream>>>(x, ln1g, ln1b, nb);
  gemm_qkv<<<768,256,0,stream>>>(nb, wgq, gqb, gkb, gvb, qbf, kbf, vtb);
  flash_kernel<<<2048,256,0,stream>>>(qbf, kbf, vtb, opart, lpart);
  reduce_o<<<2048,256,0,stream>>>(opart, lpart, obf, Ls);
  colsum_kernel<<<2048,128,0,stream>>>(qbf, kbf, Ls, colG);
  gemm64<<<512,256,0,stream>>>(obf, wgo, gob, nullptr, x, r1, 8192,256,256, 0, 1.0f);

  // ---- block 2: local attention
  ln_kernel<<<2048,256,0,stream>>>(r1, ln2g, ln2b, nb);
  gemm_qkv<<<768,256,0,stream>>>(nb, wlq, lqb, lkb, lvb, qbf, kbf, vtb);
  flash_kernel<<<2048,256,0,stream>>>(qbf, kbf, vtb, opart, lpart);
  reduce_o<<<2048,256,0,stream>>>(opart, lpart, obf, Ls);
  colsum_kernel<<<2048,128,0,stream>>>(qbf, kbf, Ls, colL);
  gemm64<<<512,256,0,stream>>>(obf, wlo, lob, nullptr, r1, r2, 8192,256,256, 0, 1.0f);

  // ---- FFN (+ residual projection fused via K=1280 concat)
  ln_kernel<<<2048,256,0,stream>>>(r2, ln3g, ln3b, nb);
  gemm_bf16<<<1024,256,0,stream>>>(nb, wf1, fb1, nullptr, Acat, 8192,1024,256, 1|2, 1.0f, 1280);
  gemm64<<<512,256,0,stream>>>(Acat, wcat, fb2, resb, r2, r3, 8192,256,1280, 0, 1.0f);

  // ---- importance -> partial ranks -> compact -> gather + BN + idx
  imp_kernel<<<64,128,0,stream>>>(colG, colL, impb);
  rank_part<<<256,256,0,stream>>>(impb, rpb);
  compact_kernel<<<NBATCH,256,0,stream>>>(rpb, KK, idxb);
  int total = NBATCH*KK;
  final_kernel<<<(total+3)/4,256,0,stream>>>(r3, idxb, bng, bnb, bnm, bnv, out, KK);
}

// Round 16
// 355.668 us; speedup vs baseline: 1.0989x; 1.0989x over previous
//
#include <hip/hip_runtime.h>

#define SEQ 2048
#define DM 256
#define NH 8
#define DKH 32
#define NBATCH 4
#define QSCALE (0.17677669529663687f * 1.4426950408889634f)   // fold log2(e): p = exp2(s)

#if __has_builtin(__builtin_amdgcn_exp2f)
#define EXP2(x) __builtin_amdgcn_exp2f(x)
#else
#define EXP2(x) exp2f(x)
#endif

typedef __attribute__((ext_vector_type(8))) __bf16 bf16x8;
typedef __attribute__((ext_vector_type(4))) float floatx4;
typedef __attribute__((ext_vector_type(8))) short short8v;
typedef __attribute__((ext_vector_type(2))) unsigned int uint2v;

__device__ inline unsigned short f2bf(float x){
  union { float f; unsigned u; } v; v.f = x;
  unsigned r = v.u + 0x7FFFu + ((v.u >> 16) & 1u);
  return (unsigned short)(r >> 16);
}
// trunc-pack two floats' high halves into one dword (low=a): 1x v_perm_b32
__device__ inline unsigned pack2bf(float a, float b){
  union { float f; unsigned u; } ua, ub; ua.f = a; ub.f = b;
  return __builtin_amdgcn_perm(ub.u, ua.u, 0x07060302u);
}

// ------------------------------------------- LayerNorm fp32 in -> bf16 out
__global__ __launch_bounds__(256) void ln_kernel(const float* __restrict__ X,
    const float* __restrict__ G, const float* __restrict__ Bv,
    unsigned short* __restrict__ Y){
  int row = blockIdx.x*4 + (threadIdx.x>>6);
  int lane = threadIdx.x & 63;
  const float4 v = *(const float4*)(X + (size_t)row*DM + lane*4);
  float s = v.x+v.y+v.z+v.w;
  #pragma unroll
  for (int off=32; off; off>>=1) s += __shfl_xor(s, off, 64);
  float mean = s * (1.0f/DM);
  float dx=v.x-mean, dy=v.y-mean, dz=v.z-mean, dw=v.w-mean;
  float ss = dx*dx+dy*dy+dz*dz+dw*dw;
  #pragma unroll
  for (int off=32; off; off>>=1) ss += __shfl_xor(ss, off, 64);
  float r = rsqrtf(ss*(1.0f/DM) + 1e-6f);
  const float4 g = *(const float4*)(G + lane*4);
  const float4 b = *(const float4*)(Bv + lane*4);
  ushort4 o;
  o.x = f2bf(dx*r*g.x + b.x);
  o.y = f2bf(dy*r*g.y + b.y);
  o.z = f2bf(dz*r*g.z + b.z);
  o.w = f2bf(dw*r*g.w + b.w);
  *(ushort4*)(Y + (size_t)row*DM + lane*4) = o;
}

// ------ batched prep: 11 weight transposes + x -> bf16 into A_cat cols 1024..
struct WtArgs {
  const float* src[12];
  unsigned short* dst[12];
  int K[12], N[12], stride[12], off[12];
  int blk0[13];
};
__global__ __launch_bounds__(256) void wtrans_all(WtArgs a){
  __shared__ unsigned short sT[64][40];
  int wi = 0;
  while (blockIdx.x >= (unsigned)a.blk0[wi+1]) ++wi;
  int blk = blockIdx.x - a.blk0[wi];
  int tid = threadIdx.x;
  if (wi == 11){
    const float* X = a.src[11];
    unsigned short* D = a.dst[11];
    int row = blk*8 + (tid>>5);
    int c8 = (tid & 31)*8;
    const float* ip = X + (size_t)row*256 + c8;
    float4 v0 = *(const float4*)ip, v1 = *(const float4*)(ip+4);
    union { short8v v; unsigned short u[8]; } pk;
    pk.u[0]=f2bf(v0.x); pk.u[1]=f2bf(v0.y); pk.u[2]=f2bf(v0.z); pk.u[3]=f2bf(v0.w);
    pk.u[4]=f2bf(v1.x); pk.u[5]=f2bf(v1.y); pk.u[6]=f2bf(v1.z); pk.u[7]=f2bf(v1.w);
    *(short8v*)(D + (size_t)row*1280 + 1024 + c8) = pk.v;
    return;
  }
  const float* W = a.src[wi];
  unsigned short* Wt = a.dst[wi];
  int K = a.K[wi], N = a.N[wi], stride = a.stride[wi], off = a.off[wi];
  int nbk = N >> 6;
  int bx = blk % nbk, by = blk / nbk;
  int k0 = by << 5, n0 = bx << 6;
  int r = tid >> 3, cs = (tid & 7) << 3;
  const float* ip = W + (size_t)(k0+r)*N + n0 + cs;
  float4 av = *(const float4*)ip;
  float4 bq = *(const float4*)(ip+4);
  sT[cs+0][r]=f2bf(av.x); sT[cs+1][r]=f2bf(av.y); sT[cs+2][r]=f2bf(av.z); sT[cs+3][r]=f2bf(av.w);
  sT[cs+4][r]=f2bf(bq.x); sT[cs+5][r]=f2bf(bq.y); sT[cs+6][r]=f2bf(bq.z); sT[cs+7][r]=f2bf(bq.w);
  __syncthreads();
  int n = tid >> 2, kc = (tid & 3) << 3;
  *(short8v*)(Wt + (size_t)(n0+n)*stride + off + k0 + kc) = *(const short8v*)(&sT[n][kc]);
}

// ---------------------------------------------- bf16 MFMA GEMM, 128x64 tile
__global__ __launch_bounds__(256) void gemm_bf16(const unsigned short* __restrict__ A,
    const unsigned short* __restrict__ Bt, const float* __restrict__ bias,
    const float* __restrict__ Res, void* __restrict__ Cout,
    int M, int N, int K, int flags, float outscale, int ldc){
  __shared__ unsigned short sA[8192];
  __shared__ unsigned short sB[4096];
  int nbk = N >> 6;
  int bx = blockIdx.x % nbk, by = blockIdx.x / nbk;
  int m0 = by << 7, n0 = bx << 6;
  int tid = threadIdx.x, w = tid >> 6, lane = tid & 63;
  int m16 = lane & 15, quad = lane >> 4;
  int wr = w & 1, wc = w >> 1;
  const unsigned short* pa[4]; const unsigned short* pb[2];
  #pragma unroll
  for (int i=0;i<4;++i){
    int c = tid + i*256;
    int l = c & 63, kk = (c>>6)&1, mt = c>>7;
    pa[i] = A + (size_t)(m0 + mt*16 + (l&15))*K + kk*32 + ((l>>4)<<3);
  }
  #pragma unroll
  for (int i=0;i<2;++i){
    int c = tid + i*256;
    int l = c & 63, kk = (c>>6)&1, nt = c>>7;
    pb[i] = Bt + (size_t)(n0 + nt*16 + (l&15))*K + kk*32 + ((l>>4)<<3);
  }
  short8v ar[4], br[2];
  #pragma unroll
  for (int i=0;i<4;++i) ar[i] = *(const short8v*)pa[i];
  #pragma unroll
  for (int i=0;i<2;++i) br[i] = *(const short8v*)pb[i];
  floatx4 acc[4][2];
  #pragma unroll
  for (int i=0;i<4;++i){ acc[i][0]=(floatx4){0,0,0,0}; acc[i][1]=(floatx4){0,0,0,0}; }
  for (int k0=0; k0<K; k0+=64){
    __syncthreads();
    #pragma unroll
    for (int i=0;i<4;++i) *(short8v*)(sA + (tid+i*256)*8) = ar[i];
    #pragma unroll
    for (int i=0;i<2;++i) *(short8v*)(sB + (tid+i*256)*8) = br[i];
    __syncthreads();
    if (k0 + 64 < K){
      #pragma unroll
      for (int i=0;i<4;++i) ar[i] = *(const short8v*)(pa[i] + k0 + 64);
      #pragma unroll
      for (int i=0;i<2;++i) br[i] = *(const short8v*)(pb[i] + k0 + 64);
    }
    #pragma unroll
    for (int kk=0;kk<2;++kk){
      bf16x8 bf0 = *(const bf16x8*)(sB + (((wc*2+0)*2+kk)*64 + lane)*8);
      bf16x8 bf1 = *(const bf16x8*)(sB + (((wc*2+1)*2+kk)*64 + lane)*8);
      #pragma unroll
      for (int mt=0;mt<4;++mt){
        bf16x8 af = *(const bf16x8*)(sA + (((wr*4+mt)*2+kk)*64 + lane)*8);
        acc[mt][0] = __builtin_amdgcn_mfma_f32_16x16x32_bf16(af, bf0, acc[mt][0], 0,0,0);
        acc[mt][1] = __builtin_amdgcn_mfma_f32_16x16x32_bf16(af, bf1, acc[mt][1], 0,0,0);
      }
    }
  }
  float b0 = bias ? bias[n0 + wc*32 + m16]      : 0.0f;
  float b1 = bias ? bias[n0 + wc*32 + 16 + m16] : 0.0f;
  #pragma unroll
  for (int mt=0;mt<4;++mt){
    #pragma unroll
    for (int r=0;r<4;++r){
      size_t row = (size_t)m0 + wr*64 + mt*16 + quad*4 + r;
      int col0 = n0 + wc*32 + m16, col1 = col0 + 16;
      float v0 = acc[mt][0][r] + b0, v1 = acc[mt][1][r] + b1;
      if (Res){ v0 += Res[row*N + col0]; v1 += Res[row*N + col1]; }
      if (flags & 1){ v0 = fmaxf(v0, 0.0f); v1 = fmaxf(v1, 0.0f); }
      v0 *= outscale; v1 *= outscale;
      if (flags & 2){
        unsigned short* C = (unsigned short*)Cout;
        C[row*ldc + col0] = f2bf(v0); C[row*ldc + col1] = f2bf(v1);
      } else {
        float* C = (float*)Cout;
        C[row*ldc + col0] = v0; C[row*ldc + col1] = v1;
      }
    }
  }
}

// --------------------------------------------- bf16 MFMA GEMM, 64x64 tile
__global__ __launch_bounds__(256) void gemm64(const unsigned short* __restrict__ A,
    const unsigned short* __restrict__ Bt, const float* __restrict__ bias,
    const float* __restrict__ bias2, const float* __restrict__ Res,
    void* __restrict__ Cout, int M, int N, int K, int flags, float outscale){
  __shared__ unsigned short sA[4096];
  __shared__ unsigned short sB[4096];
  int nbk = N >> 6;
  int bx = blockIdx.x % nbk, by = blockIdx.x / nbk;
  int m0 = by << 6, n0 = bx << 6;
  int tid = threadIdx.x, w = tid >> 6, lane = tid & 63;
  int m16 = lane & 15, quad = lane >> 4;
  int wr = w & 1, wc = w >> 1;
  const unsigned short* pa[2]; const unsigned short* pb[2];
  #pragma unroll
  for (int i=0;i<2;++i){
    int c = tid + i*256;
    int l = c & 63, kk = (c>>6)&1, mt = c>>7;
    int col = kk*32 + ((l>>4)<<3);
    pa[i] = A  + (size_t)(m0 + mt*16 + (l&15))*K + col;
    pb[i] = Bt + (size_t)(n0 + mt*16 + (l&15))*K + col;
  }
  short8v ar[2], br[2];
  #pragma unroll
  for (int i=0;i<2;++i){ ar[i] = *(const short8v*)pa[i]; br[i] = *(const short8v*)pb[i]; }
  floatx4 acc[2][2];
  acc[0][0]=(floatx4){0,0,0,0}; acc[0][1]=(floatx4){0,0,0,0};
  acc[1][0]=(floatx4){0,0,0,0}; acc[1][1]=(floatx4){0,0,0,0};
  for (int k0=0; k0<K; k0+=64){
    __syncthreads();
    #pragma unroll
    for (int i=0;i<2;++i){
      *(short8v*)(sA + (tid+i*256)*8) = ar[i];
      *(short8v*)(sB + (tid+i*256)*8) = br[i];
    }
    __syncthreads();
    if (k0 + 64 < K){
      #pragma unroll
      for (int i=0;i<2;++i){ ar[i] = *(const short8v*)(pa[i]+k0+64); br[i] = *(const short8v*)(pb[i]+k0+64); }
    }
    #pragma unroll
    for (int kk=0;kk<2;++kk){
      bf16x8 bf0 = *(const bf16x8*)(sB + (((wc*2+0)*2+kk)*64 + lane)*8);
      bf16x8 bf1 = *(const bf16x8*)(sB + (((wc*2+1)*2+kk)*64 + lane)*8);
      bf16x8 af0 = *(const bf16x8*)(sA + (((wr*2+0)*2+kk)*64 + lane)*8);
      bf16x8 af1 = *(const bf16x8*)(sA + (((wr*2+1)*2+kk)*64 + lane)*8);
      acc[0][0] = __builtin_amdgcn_mfma_f32_16x16x32_bf16(af0, bf0, acc[0][0], 0,0,0);
      acc[0][1] = __builtin_amdgcn_mfma_f32_16x16x32_bf16(af0, bf1, acc[0][1], 0,0,0);
      acc[1][0] = __builtin_amdgcn_mfma_f32_16x16x32_bf16(af1, bf0, acc[1][0], 0,0,0);
      acc[1][1] = __builtin_amdgcn_mfma_f32_16x16x32_bf16(af1, bf1, acc[1][1], 0,0,0);
    }
  }
  float b0 = bias ? bias[n0 + wc*32 + m16]      : 0.0f;
  float b1 = bias ? bias[n0 + wc*32 + 16 + m16] : 0.0f;
  if (bias2){ b0 += bias2[n0 + wc*32 + m16]; b1 += bias2[n0 + wc*32 + 16 + m16]; }
  #pragma unroll
  for (int mt=0;mt<2;++mt){
    #pragma unroll
    for (int r=0;r<4;++r){
      size_t row = (size_t)m0 + (wr*2+mt)*16 + quad*4 + r;
      int col0 = n0 + wc*32 + m16, col1 = col0 + 16;
      float v0 = acc[mt][0][r] + b0, v1 = acc[mt][1][r] + b1;
      if (Res){ v0 += Res[row*N + col0]; v1 += Res[row*N + col1]; }
      if (flags & 1){ v0 = fmaxf(v0, 0.0f); v1 = fmaxf(v1, 0.0f); }
      v0 *= outscale; v1 *= outscale;
      if (flags & 2){
        unsigned short* C = (unsigned short*)Cout;
        C[row*N + col0] = f2bf(v0); C[row*N + col1] = f2bf(v1);
      } else {
        float* C = (float*)Cout;
        C[row*N + col0] = v0; C[row*N + col1] = v1;
      }
    }
  }
}

// ---------------------- fused QKV GEMM: A[8192x256] @ wqkv[768x256]^T
// seg2 -> V transposed into Vt[(b*8+h)*32+d][t'] with SLOT-PERMUTED t':
// flash's PV A-fragment is then the lane's own packed P registers.
__global__ __launch_bounds__(256) void gemm_qkv(const unsigned short* __restrict__ A,
    const unsigned short* __restrict__ Bt,
    const float* __restrict__ bq, const float* __restrict__ bk, const float* __restrict__ bv,
    unsigned short* __restrict__ outq, unsigned short* __restrict__ outk,
    unsigned short* __restrict__ outvt){
  __shared__ unsigned short sA[8192];
  __shared__ unsigned short sB[4096];
  int bx = blockIdx.x % 12, by = blockIdx.x / 12;
  int m0 = by << 7, n0 = bx << 6;
  int tid = threadIdx.x, w = tid >> 6, lane = tid & 63;
  int m16 = lane & 15, quad = lane >> 4;
  int wr = w & 1, wc = w >> 1;
  const unsigned short* pa[4]; const unsigned short* pb[2];
  #pragma unroll
  for (int i=0;i<4;++i){
    int c = tid + i*256;
    int l = c & 63, kk = (c>>6)&1, mt = c>>7;
    pa[i] = A + (size_t)(m0 + mt*16 + (l&15))*256 + kk*32 + ((l>>4)<<3);
  }
  #pragma unroll
  for (int i=0;i<2;++i){
    int c = tid + i*256;
    int l = c & 63, kk = (c>>6)&1, nt = c>>7;
    pb[i] = Bt + (size_t)(n0 + nt*16 + (l&15))*256 + kk*32 + ((l>>4)<<3);
  }
  short8v ar[4], br[2];
  #pragma unroll
  for (int i=0;i<4;++i) ar[i] = *(const short8v*)pa[i];
  #pragma unroll
  for (int i=0;i<2;++i) br[i] = *(const short8v*)pb[i];
  floatx4 acc[4][2];
  #pragma unroll
  for (int i=0;i<4;++i){ acc[i][0]=(floatx4){0,0,0,0}; acc[i][1]=(floatx4){0,0,0,0}; }
  for (int k0=0; k0<256; k0+=64){
    __syncthreads();
    #pragma unroll
    for (int i=0;i<4;++i) *(short8v*)(sA + (tid+i*256)*8) = ar[i];
    #pragma unroll
    for (int i=0;i<2;++i) *(short8v*)(sB + (tid+i*256)*8) = br[i];
    __syncthreads();
    if (k0 + 64 < 256){
      #pragma unroll
      for (int i=0;i<4;++i) ar[i] = *(const short8v*)(pa[i] + k0 + 64);
      #pragma unroll
      for (int i=0;i<2;++i) br[i] = *(const short8v*)(pb[i] + k0 + 64);
    }
    #pragma unroll
    for (int kk=0;kk<2;++kk){
      bf16x8 bf0 = *(const bf16x8*)(sB + (((wc*2+0)*2+kk)*64 + lane)*8);
      bf16x8 bf1 = *(const bf16x8*)(sB + (((wc*2+1)*2+kk)*64 + lane)*8);
      #pragma unroll
      for (int mt=0;mt<4;++mt){
        bf16x8 af = *(const bf16x8*)(sA + (((wr*4+mt)*2+kk)*64 + lane)*8);
        acc[mt][0] = __builtin_amdgcn_mfma_f32_16x16x32_bf16(af, bf0, acc[mt][0], 0,0,0);
        acc[mt][1] = __builtin_amdgcn_mfma_f32_16x16x32_bf16(af, bf1, acc[mt][1], 0,0,0);
      }
    }
  }
  int seg = n0 >> 8;
  int nb  = n0 & 255;
  const float* bias = (seg==0) ? bq : ((seg==1) ? bk : bv);
  float b0 = bias[nb + wc*32 + m16];
  float b1 = bias[nb + wc*32 + 16 + m16];
  if (seg == 2){
    int b = m0 >> 11;
    int t0 = (m0 & 2047) + wr*64 + quad*4;
    #pragma unroll
    for (int mt=0;mt<4;++mt){
      int tt = t0 + mt*16;
      // slot permutation within 32-key group (tt is 4-aligned)
      int tp = (tt & ~31) | (((tt>>2)&3)<<3) | (((tt>>4)&1)<<2);
      #pragma unroll
      for (int cc=0;cc<2;++cc){
        int col = nb + wc*32 + m16 + cc*16;
        float bb = cc ? b1 : b0;
        int hh = col >> 5, dd = col & 31;
        uint2v pk;
        pk.x = (unsigned)f2bf(acc[mt][cc][0]+bb) | ((unsigned)f2bf(acc[mt][cc][1]+bb) << 16);
        pk.y = (unsigned)f2bf(acc[mt][cc][2]+bb) | ((unsigned)f2bf(acc[mt][cc][3]+bb) << 16);
        *(uint2v*)(outvt + ((size_t)((b*8+hh)*32+dd))*SEQ + tp) = pk;
      }
    }
  } else {
    unsigned short* C = (seg==0) ? outq : outk;
    float scale = (seg==0) ? QSCALE : 1.0f;
    #pragma unroll
    for (int mt=0;mt<4;++mt){
      #pragma unroll
      for (int r=0;r<4;++r){
        size_t row = (size_t)m0 + wr*64 + mt*16 + quad*4 + r;
        int col0 = nb + wc*32 + m16, col1 = col0 + 16;
        C[row*256 + col0] = f2bf((acc[mt][0][r] + b0)*scale);
        C[row*256 + col1] = f2bf((acc[mt][1][r] + b1)*scale);
      }
    }
  }
}

// ---------------- flash v9: S^T, P-in-registers (slot-permuted V), FULL keys
// grid = 32 qblocks(64q) x 32 (b,h); 4 waves x 16 q; LDS 16.4KB, 0 conflicts.
// Direct bf16 O + inv-l epilogue (no partials, no extra HBM round-trip).
__global__ __launch_bounds__(256) void flash_kernel(
    const unsigned short* __restrict__ Qb, const unsigned short* __restrict__ Kb,
    const unsigned short* __restrict__ Vt, unsigned short* __restrict__ Obf,
    float* __restrict__ Lout){
  __shared__ unsigned short sK[4096];         // (kt*64+lane)*8, key=kt*16+(l&15)
  __shared__ unsigned short sV[4096];         // ((ks*2+nt)*64+lane)*8, slot order
  int qb = blockIdx.x & 31, bh = blockIdx.x >> 5;
  int h = bh & 7, b = bh >> 3;
  int tid = threadIdx.x, w = tid >> 6, lane = tid & 63;
  int m16 = lane & 15, quad = lane >> 4;
  int qrow0 = qb*64 + w*16;
  bf16x8 qf = *(const bf16x8*)(Qb + (size_t)(b*SEQ + qrow0 + m16)*DM + h*DKH + quad*8);
  floatx4 o0 = {0,0,0,0}, o1 = {0,0,0,0};
  float l0 = 0.f;

  const unsigned short* kp[2]; const unsigned short* vp[2];
  #pragma unroll
  for (int i=0;i<2;++i){
    int c = tid + i*256, l = c & 63;
    int kt = c >> 6;
    kp[i] = Kb + (size_t)(b*SEQ + kt*16 + (l&15))*DM + h*DKH + ((l>>4)<<3);
    int nt = (c>>6)&1, ks = c>>7;
    vp[i] = Vt + (size_t)(bh*DKH + nt*16 + (l&15))*SEQ + ks*32 + ((l>>4)<<3);
  }
  short8v kr[2], vr[2];
  #pragma unroll
  for (int i=0;i<2;++i){ kr[i] = *(const short8v*)kp[i]; vr[i] = *(const short8v*)vp[i]; }

  for (int t0=0; t0<SEQ; t0+=128){
    __syncthreads();
    #pragma unroll
    for (int i=0;i<2;++i){
      *(short8v*)(sK + (tid+i*256)*8) = kr[i];
      *(short8v*)(sV + (tid+i*256)*8) = vr[i];
    }
    __syncthreads();
    if (t0 + 128 < SEQ){
      #pragma unroll
      for (int i=0;i<2;++i){
        kr[i] = *(const short8v*)(kp[i] + (size_t)(t0+128)*DM);
        vr[i] = *(const short8v*)(vp[i] + (t0+128));
      }
    }
    // per 32-key group: two S^T MFMAs -> exp -> pack -> PV A-frag IN REGISTERS
    #pragma unroll
    for (int ks=0;ks<4;++ks){
      bf16x8 kf0 = *(const bf16x8*)(sK + ((ks*2+0)*64+lane)*8);
      bf16x8 kf1 = *(const bf16x8*)(sK + ((ks*2+1)*64+lane)*8);
      floatx4 z = {0,0,0,0};
      floatx4 s0 = __builtin_amdgcn_mfma_f32_16x16x32_bf16(kf0, qf, z, 0,0,0);
      floatx4 s1 = __builtin_amdgcn_mfma_f32_16x16x32_bf16(kf1, qf, z, 0,0,0);
      float p0 = EXP2(s0[0]), p1 = EXP2(s0[1]), p2 = EXP2(s0[2]), p3 = EXP2(s0[3]);
      float p4 = EXP2(s1[0]), p5 = EXP2(s1[1]), p6 = EXP2(s1[2]), p7 = EXP2(s1[3]);
      l0 += ((p0+p1)+(p2+p3)) + ((p4+p5)+(p6+p7));
      union { bf16x8 v; unsigned u[4]; } pf;
      pf.u[0] = pack2bf(p0,p1); pf.u[1] = pack2bf(p2,p3);
      pf.u[2] = pack2bf(p4,p5); pf.u[3] = pack2bf(p6,p7);
      bf16x8 vf0 = *(const bf16x8*)(sV + ((ks*2+0)*64+lane)*8);
      bf16x8 vf1 = *(const bf16x8*)(sV + ((ks*2+1)*64+lane)*8);
      o0 = __builtin_amdgcn_mfma_f32_16x16x32_bf16(pf.v, vf0, o0, 0,0,0);
      o1 = __builtin_amdgcn_mfma_f32_16x16x32_bf16(pf.v, vf1, o1, 0,0,0);
    }
  }
  // l0: per-lane partial for q = qrow0+m16; sum over quads
  l0 += __shfl_xor(l0, 16, 64);
  l0 += __shfl_xor(l0, 32, 64);
  float inv = 1.0f / l0;
  #pragma unroll
  for (int r=0;r<4;++r){
    float iv = __shfl(inv, quad*4 + r, 64);   // lane (quad*4+r) holds q = qrow0+quad*4+r
    int q = qrow0 + quad*4 + r;
    size_t base = (size_t)(b*SEQ + q)*DM + h*DKH;
    Obf[base + m16]      = f2bf(o0[r]*iv);
    Obf[base + 16 + m16] = f2bf(o1[r]*iv);
    if (m16 == 0) Lout[(size_t)bh*SEQ + q] = iv;
  }
}

// --------------- colsum: LDS-staged, q-range split x2, raw exp
__global__ __launch_bounds__(128) void colsum_kernel(
    const unsigned short* __restrict__ Qb, const unsigned short* __restrict__ Kb,
    const float* __restrict__ Lv, float* __restrict__ col){
  __shared__ unsigned short sQ[2048];
  __shared__ float sL[64];
  int kc = blockIdx.x & 31;
  int rest = blockIdx.x >> 5;
  int bh = rest & 31;
  int half = rest >> 5;
  int h = bh & 7, b = bh >> 3;
  int tid = threadIdx.x, w = tid >> 6, lane = tid & 63;
  int m16 = lane & 15, quad = lane >> 4;
  int key0 = kc*64 + w*32;
  const unsigned short* kp = Kb + (size_t)(b*SEQ + key0 + m16)*DM + h*DKH + quad*8;
  bf16x8 kf0 = *(const bf16x8*)kp;
  bf16x8 kf1 = *(const bf16x8*)(kp + 16*DM);
  float acc0[4] = {0,0,0,0}, acc1[4] = {0,0,0,0};
  const unsigned short* qp[2];
  #pragma unroll
  for (int i=0;i<2;++i){
    int c = tid + i*128, l = c & 63, qt = c >> 6;
    qp[i] = Qb + (size_t)(b*SEQ + half*1024 + qt*16 + (l&15))*DM + h*DKH + ((l>>4)<<3);
  }
  short8v qr[2];
  #pragma unroll
  for (int i=0;i<2;++i) qr[i] = *(const short8v*)qp[i];
  float lr = (tid < 64) ? Lv[(size_t)bh*SEQ + half*1024 + tid] : 0.0f;
  for (int q0=0; q0<1024; q0+=64){
    __syncthreads();
    #pragma unroll
    for (int i=0;i<2;++i) *(short8v*)(sQ + (tid+i*128)*8) = qr[i];
    if (tid < 64) sL[tid] = lr;
    __syncthreads();
    if (q0 + 64 < 1024){
      #pragma unroll
      for (int i=0;i<2;++i) qr[i] = *(const short8v*)(qp[i] + (size_t)(q0+64)*DM);
      if (tid < 64) lr = Lv[(size_t)bh*SEQ + half*1024 + q0 + 64 + tid];
    }
    floatx4 z = {0,0,0,0};
    #pragma unroll
    for (int qt2=0;qt2<4;++qt2){
      bf16x8 qf = *(const bf16x8*)(sQ + (qt2*64+lane)*8);
      floatx4 t0 = __builtin_amdgcn_mfma_f32_16x16x32_bf16(kf0, qf, z, 0,0,0);
      floatx4 t1 = __builtin_amdgcn_mfma_f32_16x16x32_bf16(kf1, qf, z, 0,0,0);
      float lq = sL[qt2*16+m16];
      #pragma unroll
      for (int r=0;r<4;++r){ acc0[r] += EXP2(t0[r])*lq; acc1[r] += EXP2(t1[r])*lq; }
    }
  }
  #pragma unroll
  for (int r=0;r<4;++r){
    float v0 = acc0[r], v1 = acc1[r];
    v0 += __shfl_xor(v0, 1, 64); v0 += __shfl_xor(v0, 2, 64);
    v0 += __shfl_xor(v0, 4, 64); v0 += __shfl_xor(v0, 8, 64);
    v1 += __shfl_xor(v1, 1, 64); v1 += __shfl_xor(v1, 2, 64);
    v1 += __shfl_xor(v1, 4, 64); v1 += __shfl_xor(v1, 8, 64);
    if (m16 == 0){
      size_t base = (size_t)(half*32 + bh)*SEQ;
      col[base + key0 + quad*4 + r]      = v0;
      col[base + key0 + 16 + quad*4 + r] = v1;
    }
  }
}

// ------------------------------------- importance = 0.7*G + 0.3*L (fp64 acc)
__global__ __launch_bounds__(128) void imp_kernel(const float* __restrict__ colG,
    const float* __restrict__ colL, float* __restrict__ imp){
  int i = blockIdx.x*128 + threadIdx.x;
  int b = i >> 11, t = i & 2047;
  double sg = 0.0, sl = 0.0;
  for (int h=0; h<8; ++h){
    size_t i0 = (size_t)(b*8+h)*SEQ + t;
    size_t i1 = (size_t)(32 + b*8+h)*SEQ + t;
    sg += (double)colG[i0] + (double)colG[i1];
    sl += (double)colL[i0] + (double)colL[i1];
  }
  imp[i] = (float)(0.7*sg + 0.3*sl);
}

// --------------------- partial ranks (desc value, asc index tie-break)
__global__ __launch_bounds__(256) void rank_part(const float* __restrict__ imp,
    int* __restrict__ rp){
  __shared__ float sj[256];
  int jc = blockIdx.x & 7;
  int ic = (blockIdx.x >> 3) & 7;
  int b  = blockIdx.x >> 6;
  int tid = threadIdx.x;
  sj[tid] = imp[b*2048 + jc*256 + tid];
  __syncthreads();
  int i = ic*256 + tid;
  float v = imp[b*2048 + i];
  int jbase = jc*256;
  int r = 0;
  #pragma unroll 4
  for (int j=0; j<256; j+=4){
    float4 vj = *(const float4*)&sj[j];
    r += (vj.x > v) || (vj.x == v && (jbase+j+0) < i);
    r += (vj.y > v) || (vj.y == v && (jbase+j+1) < i);
    r += (vj.z > v) || (vj.z == v && (jbase+j+2) < i);
    r += (vj.w > v) || (vj.w == v && (jbase+j+3) < i);
  }
  rp[(size_t)jc*8192 + b*2048 + i] = r;
}

// --------------------- compact indices with rank < KK (ascending order)
__global__ __launch_bounds__(256) void compact_kernel(const int* __restrict__ rp,
    int KK, int* __restrict__ idxout){
  __shared__ int swave[4];
  int b = blockIdx.x;
  int tid = threadIdx.x, w = tid >> 6, lane = tid & 63;
  int base = tid*8;
  int f[8]; int c = 0;
  #pragma unroll
  for (int j=0;j<8;++j){
    int rr = 0;
    #pragma unroll
    for (int c2=0;c2<8;++c2) rr += rp[(size_t)c2*8192 + b*2048 + base + j];
    f[j] = (rr < KK) ? 1 : 0; c += f[j];
  }
  int pref = c;
  #pragma unroll
  for (int off=1; off<64; off<<=1){
    int t = __shfl_up(pref, off, 64);
    if (lane >= off) pref += t;
  }
  if (lane == 63) swave[w] = pref;
  __syncthreads();
  int wbase = 0;
  for (int k=0;k<w;++k) wbase += swave[k];
  int pos = wbase + pref - c;
  #pragma unroll
  for (int j=0;j<8;++j){
    if (f[j]) idxout[b*KK + pos++] = base + j;
  }
}

// --------------------------------------- gather + BatchNorm + write idx
__global__ __launch_bounds__(256) void final_kernel(const float* __restrict__ rb,
    const int* __restrict__ idx, const float* __restrict__ g, const float* __restrict__ bt,
    const float* __restrict__ mean, const float* __restrict__ var,
    float* __restrict__ out, int KK){
  int row = blockIdx.x*4 + (threadIdx.x>>6);
  int lane = threadIdx.x & 63;
  int total = NBATCH*KK;
  if (row < total){
    int b = row / KK;
    int src = idx[row];
    float4 v  = *(const float4*)(rb + ((size_t)(b*SEQ+src))*DM + lane*4);
    float4 gm = *(const float4*)(mean + lane*4);
    float4 gv = *(const float4*)(var  + lane*4);
    float4 gg = *(const float4*)(g    + lane*4);
    float4 gb = *(const float4*)(bt   + lane*4);
    float4 o;
    o.x = (v.x-gm.x)*rsqrtf(gv.x+1e-3f)*gg.x + gb.x;
    o.y = (v.y-gm.y)*rsqrtf(gv.y+1e-3f)*gg.y + gb.y;
    o.z = (v.z-gm.z)*rsqrtf(gv.z+1e-3f)*gg.z + gb.z;
    o.w = (v.w-gm.w)*rsqrtf(gv.w+1e-3f)*gg.w + gb.w;
    *(float4*)(out + (size_t)row*DM + lane*4) = o;
  }
  int gid = blockIdx.x*256 + threadIdx.x;
  if (gid < total) out[(size_t)total*DM + gid] = (float)idx[gid];
}

// ================================================================== launch
extern "C" void kernel_launch(void* const* d_in, const int* in_sizes, int n_in,
                              void* d_out, int out_size, void* d_ws, size_t ws_size,
                              hipStream_t stream){
  (void)in_sizes; (void)n_in; (void)ws_size;
  const float* x    = (const float*)d_in[0];
  const float* ln1g = (const float*)d_in[1];
  const float* ln1b = (const float*)d_in[2];
  const float* ln2g = (const float*)d_in[3];
  const float* ln2b = (const float*)d_in[4];
  const float* ln3g = (const float*)d_in[5];
  const float* ln3b = (const float*)d_in[6];
  const float* gqw = (const float*)d_in[7];  const float* gqb = (const float*)d_in[8];
  const float* gkw = (const float*)d_in[9];  const float* gkb = (const float*)d_in[10];
  const float* gvw = (const float*)d_in[11]; const float* gvb = (const float*)d_in[12];
  const float* gow = (const float*)d_in[13]; const float* gob = (const float*)d_in[14];
  const float* lqw = (const float*)d_in[15]; const float* lqb = (const float*)d_in[16];
  const float* lkw = (const float*)d_in[17]; const float* lkb = (const float*)d_in[18];
  const float* lvw = (const float*)d_in[19]; const float* lvb = (const float*)d_in[20];
  const float* low = (const float*)d_in[21]; const float* lob = (const float*)d_in[22];
  const float* fw1 = (const float*)d_in[23]; const float* fb1 = (const float*)d_in[24];
  const float* fw2 = (const float*)d_in[25]; const float* fb2 = (const float*)d_in[26];
  const float* resw = (const float*)d_in[27]; const float* resb = (const float*)d_in[28];
  const float* bng = (const float*)d_in[29]; const float* bnb = (const float*)d_in[30];
  const float* bnm = (const float*)d_in[31]; const float* bnv = (const float*)d_in[32];

  float* ws = (float*)d_ws;
  const size_t M1 = 2097152;                 // B*S*D
  float* r1 = ws;
  float* r2 = ws + M1;
  float* r3 = ws + 2*M1;
  unsigned short* nb  = (unsigned short*)(ws + 3*M1);
  unsigned short* qbf = (unsigned short*)(ws + 3*M1 + M1/2);
  unsigned short* kbf = (unsigned short*)(ws + 4*M1);
  unsigned short* vtb = (unsigned short*)(ws + 4*M1 + M1/2);
  unsigned short* obf = (unsigned short*)(ws + 5*M1);
  unsigned short* Acat = (unsigned short*)(ws + 6*M1);  // 8192x1280 bf16: 6*M1..8.5*M1
  unsigned short* wT  = (unsigned short*)(ws + 9*M1);
  unsigned short* wgq = wT;            unsigned short* wgk = wT + 65536;
  unsigned short* wgv = wT + 131072;   unsigned short* wgo = wT + 196608;
  unsigned short* wlq = wT + 262144;   unsigned short* wlk = wT + 327680;
  unsigned short* wlv = wT + 393216;   unsigned short* wlo = wT + 458752;
  unsigned short* wf1  = wT + 524288;  // [1024][256]
  unsigned short* wcat = wT + 786432;  // [256][1280] = wf2^T | resw^T
  float* Ls    = ws + 10*M1;                      // 65536 (inv l)
  float* colG  = ws + 10*M1 + 65536;              // 2 halves x 32 bh x 2048
  float* colL  = ws + 10*M1 + 196608;
  float* impb  = ws + 10*M1 + 327680;             // 8192
  int*   rpb   = (int*)(ws + 10*M1 + 335872);     // 8 x 8192 partial ranks
  int*   idxb  = (int*)(ws + 10*M1 + 401408);

  int KK = out_size / (NBATCH*(DM+1));
  float* out = (float*)d_out;

  // ---- prep: 11 weight transposes + x->bf16 into Acat cols 1024.. (one launch)
  WtArgs wa;
  const float* srcs[12] = {gqw,gkw,gvw,gow,lqw,lkw,lvw,low, fw1, fw2, resw, x};
  unsigned short* dsts[12] = {wgq,wgk,wgv,wgo,wlq,wlk,wlv,wlo, wf1, wcat, wcat, Acat};
  int Ks[12]  = {256,256,256,256,256,256,256,256, 256, 1024, 256, 0};
  int Ns[12]  = {256,256,256,256,256,256,256,256, 1024, 256, 256, 0};
  int Ss[12]  = {256,256,256,256,256,256,256,256, 256, 1280, 1280, 0};
  int Os[12]  = {0,0,0,0,0,0,0,0, 0, 0, 1024, 0};
  int acc = 0;
  for (int i=0;i<12;++i){
    wa.src[i]=srcs[i]; wa.dst[i]=dsts[i]; wa.K[i]=Ks[i]; wa.N[i]=Ns[i];
    wa.stride[i]=Ss[i]; wa.off[i]=Os[i];
    wa.blk0[i]=acc;
    acc += (i==11) ? 1024 : (Ks[i]>>5)*(Ns[i]>>6);
  }
  wa.blk0[12]=acc;
  wtrans_all<<<acc,256,0,stream>>>(wa);

  // ---- block 1: global attention
  ln_kernel<<<2048,256,0,stream>>>(x, ln1g, ln1b, nb);
  gemm_qkv<<<768,256,0,stream>>>(nb, wgq, gqb, gkb, gvb, qbf, kbf, vtb);
  flash_kernel<<<1024,256,0,stream>>>(qbf, kbf, vtb, obf, Ls);
  colsum_kernel<<<2048,128,0,stream>>>(qbf, kbf, Ls, colG);
  gemm64<<<512,256,0,stream>>>(obf, wgo, gob, nullptr, x, r1, 8192,256,256, 0, 1.0f);

  // ---- block 2: local attention
  ln_kernel<<<2048,256,0,stream>>>(r1, ln2g, ln2b, nb);
  gemm_qkv<<<768,256,0,stream>>>(nb, wlq, lqb, lkb, lvb, qbf, kbf, vtb);
  flash_kernel<<<1024,256,0,stream>>>(qbf, kbf, vtb, obf, Ls);
  colsum_kernel<<<2048,128,0,stream>>>(qbf, kbf, Ls, colL);
  gemm64<<<512,256,0,stream>>>(obf, wlo, lob, nullptr, r1, r2, 8192,256,256, 0, 1.0f);

  // ---- FFN (+ residual projection fused via K=1280 concat)
  ln_kernel<<<2048,256,0,stream>>>(r2, ln3g, ln3b, nb);
  gemm_bf16<<<1024,256,0,stream>>>(nb, wf1, fb1, nullptr, Acat, 8192,1024,256, 1|2, 1.0f, 1280);
  gemm64<<<512,256,0,stream>>>(Acat, wcat, fb2, resb, r2, r3, 8192,256,1280, 0, 1.0f);

  // ---- importance -> partial ranks -> compact -> gather + BN + idx
  imp_kernel<<<64,128,0,stream>>>(colG, colL, impb);
  rank_part<<<256,256,0,stream>>>(impb, rpb);
  compact_kernel<<<NBATCH,256,0,stream>>>(rpb, KK, idxb);
  int total = NBATCH*KK;
  final_kernel<<<(total+3)/4,256,0,stream>>>(r3, idxb, bng, bnb, bnm, bnv, out, KK);
}